// Round 1
// baseline (2424.703 us; speedup 1.0000x reference)
//
#include <hip/hip_runtime.h>
#include <math.h>

#define N_SEQ  4096
#define C_TOT  768
#define NBLK   4
#define BS     192
#define B_BATCH 8
#define RT     16
#define RTP    20          // padded row stride (floats) to break LDS bank conflicts
#define LAMBDA 0.01f

// ---------------------------------------------------------------------------
// Stockham radix-2 FFT core (N=4096), 256 threads, ping-pong LDS buffers.
// sign = -1 forward, +1 inverse (unnormalized both ways).
// Verified butterfly: k = i & (p-1); j = ((i-k)<<1)+k; dst[j] = u + w*v,
// dst[j+p] = u - w*v with w = exp(sign*i*pi*k/p).
// ---------------------------------------------------------------------------
__device__ __forceinline__ float2* stockham4096(float2* bufA, float2* bufB,
                                                int t, float sign) {
  float2* src = bufA;
  float2* dst = bufB;
  float inv_p = 1.0f;
  for (int p = 1; p < N_SEQ; p <<= 1) {
#pragma unroll
    for (int m = 0; m < 8; m++) {
      int i = t + m * 256;          // i in [0, 2048)
      int kk = i & (p - 1);
      float2 u = src[i];
      float2 v = src[i + N_SEQ / 2];
      float ang = sign * (float)M_PI * (float)kk * inv_p;
      float sn, cs;
      __sincosf(ang, &sn, &cs);
      float vr = cs * v.x - sn * v.y;
      float vi = cs * v.y + sn * v.x;
      int j = ((i - kk) << 1) + kk;
      dst[j]     = make_float2(u.x + vr, u.y + vi);
      dst[j + p] = make_float2(u.x - vr, u.y - vi);
    }
    __syncthreads();
    float2* tmp = src; src = dst; dst = tmp;
    inv_p *= 0.5f;
  }
  return src;                        // result, natural order
}

// ---------------------------------------------------------------------------
// Stage 1: forward FFT along seq axis. x (b,n,c) real -> Yr/Yi (b,c,n).
// One workgroup per (b,c) column. Unnormalized.
// ---------------------------------------------------------------------------
__global__ __launch_bounds__(256) void fft_fwd_kernel(
    const float* __restrict__ x, float* __restrict__ Yr, float* __restrict__ Yi) {
  __shared__ float2 bufA[N_SEQ];
  __shared__ float2 bufB[N_SEQ];
  const int wg = blockIdx.x;                 // b*C_TOT + c
  const int b = wg / C_TOT, c = wg % C_TOT;
  const float* xp = x + (size_t)b * N_SEQ * C_TOT + c;
  const int t = threadIdx.x;
#pragma unroll
  for (int m = 0; m < 16; m++) {
    int n = t + m * 256;
    bufA[n] = make_float2(xp[(size_t)n * C_TOT], 0.0f);
  }
  __syncthreads();
  float2* res = stockham4096(bufA, bufB, t, -1.0f);
  float* yr = Yr + (size_t)wg * N_SEQ;
  float* yi = Yi + (size_t)wg * N_SEQ;
#pragma unroll
  for (int m = 0; m < 16; m++) {
    int n = t + m * 256;
    yr[n] = res[n].x;
    yi[n] = res[n].y;
  }
}

// ---------------------------------------------------------------------------
// Stage 2: forward DFT-4 across blocks, in-place, with full ortho scale 1/128.
// z0=y0+y1+y2+y3 ; z1=y0-i*y1-y2+i*y3 ; z2=y0-y1+y2-y3 ; z3=y0+i*y1-y2-i*y3
// ---------------------------------------------------------------------------
__global__ __launch_bounds__(256) void dft4_fwd_kernel(
    float* __restrict__ Yr, float* __restrict__ Yi) {
  size_t idx = (size_t)blockIdx.x * 256 + threadIdx.x;   // over B*BS*N_SEQ
  int n = (int)(idx & (N_SEQ - 1));
  size_t rest = idx >> 12;                                // b*BS + d
  int d = (int)(rest % BS);
  int b = (int)(rest / BS);
  size_t base = ((size_t)(b * C_TOT + d)) * N_SEQ + n;
  const size_t S = (size_t)BS * N_SEQ;
  float a0r = Yr[base],         a0i = Yi[base];
  float a1r = Yr[base + S],     a1i = Yi[base + S];
  float a2r = Yr[base + 2 * S], a2i = Yi[base + 2 * S];
  float a3r = Yr[base + 3 * S], a3i = Yi[base + 3 * S];
  const float s = 1.0f / 128.0f;
  float z0r = (a0r + a1r + a2r + a3r) * s;
  float z0i = (a0i + a1i + a2i + a3i) * s;
  float z1r = (a0r + a1i - a2r - a3i) * s;
  float z1i = (a0i - a1r - a2i + a3r) * s;
  float z2r = (a0r - a1r + a2r - a3r) * s;
  float z2i = (a0i - a1i + a2i - a3i) * s;
  float z3r = (a0r - a1i - a2r + a3i) * s;
  float z3i = (a0i + a1r - a2i - a3r) * s;
  Yr[base]         = z0r; Yi[base]         = z0i;
  Yr[base + S]     = z1r; Yi[base + S]     = z1i;
  Yr[base + 2 * S] = z2r; Yi[base + 2 * S] = z2i;
  Yr[base + 3 * S] = z3r; Yi[base + 3 * S] = z3i;
}

// ---------------------------------------------------------------------------
// Stage 3: fused 2-layer complex MLP + softshrink, in-place on Yr/Yi.
// Workgroup: 192 threads (k = output channel), one (b, kb, 16-row n-tile).
// r1 = relu(zr*W10 - zi*W11 + b10) ; i1 = relu(zr*W11 + zi*W10 + b11)
// r2 = r1*W20 - i1*W21 + b20       ; i2 = r1*W21 + i1*W20 + b21
// out = softshrink(r2, i2)
// Weights w[comp][kb][d][k]; einsum sums over d, output index k.
// ---------------------------------------------------------------------------
__global__ __launch_bounds__(192) void einfft_mlp_kernel(
    float* __restrict__ Yr, float* __restrict__ Yi,
    const float* __restrict__ w1, const float* __restrict__ b1,
    const float* __restrict__ w2, const float* __restrict__ b2) {
  __shared__ float zr[BS][RTP];
  __shared__ float zi[BS][RTP];
  __shared__ float r1[BS][RTP];
  __shared__ float i1[BS][RTP];

  const int tile = blockIdx.x;   // 0..255
  const int kb   = blockIdx.y;   // 0..3
  const int b    = blockIdx.z;   // 0..7
  const int k    = threadIdx.x;  // 0..191

  float* zrp = Yr + ((size_t)(b * C_TOT + kb * BS + k)) * N_SEQ + (size_t)tile * RT;
  float* zip = Yi + ((size_t)(b * C_TOT + kb * BS + k)) * N_SEQ + (size_t)tile * RT;

  {
    const float4* gr = (const float4*)zrp;
    const float4* gi = (const float4*)zip;
    float4* lr = (float4*)&zr[k][0];
    float4* li = (float4*)&zi[k][0];
#pragma unroll
    for (int q = 0; q < RT / 4; q++) {
      lr[q] = gr[q];
      li[q] = gi[q];
    }
  }
  __syncthreads();

  float accR[RT], accI[RT];

  // ------------------- layer 1 -------------------
  {
    const float* w10 = w1 + (size_t)kb * BS * BS;
    const float* w11 = w1 + (size_t)(NBLK + kb) * BS * BS;
#pragma unroll
    for (int r = 0; r < RT; r++) { accR[r] = 0.0f; accI[r] = 0.0f; }
    for (int d = 0; d < BS; d++) {
      float wa = w10[d * BS + k];
      float wb = w11[d * BS + k];
      const float4* a4 = (const float4*)&zr[d][0];
      const float4* c4 = (const float4*)&zi[d][0];
#pragma unroll
      for (int q = 0; q < RT / 4; q++) {
        float4 a = a4[q], c = c4[q];
        accR[4*q+0] += a.x * wa - c.x * wb;
        accR[4*q+1] += a.y * wa - c.y * wb;
        accR[4*q+2] += a.z * wa - c.z * wb;
        accR[4*q+3] += a.w * wa - c.w * wb;
        accI[4*q+0] += a.x * wb + c.x * wa;
        accI[4*q+1] += a.y * wb + c.y * wa;
        accI[4*q+2] += a.z * wb + c.z * wa;
        accI[4*q+3] += a.w * wb + c.w * wa;
      }
    }
    float br = b1[(size_t)kb * BS + k];
    float bi = b1[(size_t)(NBLK + kb) * BS + k];
#pragma unroll
    for (int r = 0; r < RT; r++) {
      r1[k][r] = fmaxf(accR[r] + br, 0.0f);
      i1[k][r] = fmaxf(accI[r] + bi, 0.0f);
    }
  }
  __syncthreads();

  // ------------------- layer 2 + softshrink -------------------
  {
    const float* w20 = w2 + (size_t)kb * BS * BS;
    const float* w21 = w2 + (size_t)(NBLK + kb) * BS * BS;
#pragma unroll
    for (int r = 0; r < RT; r++) { accR[r] = 0.0f; accI[r] = 0.0f; }
    for (int d = 0; d < BS; d++) {
      float wa = w20[d * BS + k];
      float wb = w21[d * BS + k];
      const float4* a4 = (const float4*)&r1[d][0];
      const float4* c4 = (const float4*)&i1[d][0];
#pragma unroll
      for (int q = 0; q < RT / 4; q++) {
        float4 a = a4[q], c = c4[q];
        accR[4*q+0] += a.x * wa - c.x * wb;
        accR[4*q+1] += a.y * wa - c.y * wb;
        accR[4*q+2] += a.z * wa - c.z * wb;
        accR[4*q+3] += a.w * wa - c.w * wb;
        accI[4*q+0] += a.x * wb + c.x * wa;
        accI[4*q+1] += a.y * wb + c.y * wa;
        accI[4*q+2] += a.z * wb + c.z * wa;
        accI[4*q+3] += a.w * wb + c.w * wa;
      }
    }
    float br = b2[(size_t)kb * BS + k];
    float bi = b2[(size_t)(NBLK + kb) * BS + k];
#pragma unroll
    for (int r = 0; r < RT; r++) {
      float vr = accR[r] + br;
      float vi = accI[r] + bi;
      vr = (vr > LAMBDA) ? (vr - LAMBDA) : ((vr < -LAMBDA) ? (vr + LAMBDA) : 0.0f);
      vi = (vi > LAMBDA) ? (vi - LAMBDA) : ((vi < -LAMBDA) ? (vi + LAMBDA) : 0.0f);
      zrp[r] = vr;
      zip[r] = vi;
    }
  }
}

// ---------------------------------------------------------------------------
// Stage 4: inverse DFT-4 across blocks, in-place, scale 1/128 (full inverse
// ortho norm folded here; stage 5 is unnormalized).
// v0=z0+z1+z2+z3 ; v1=z0+i*z1-z2-i*z3 ; v2=z0-z1+z2-z3 ; v3=z0-i*z1-z2+i*z3
// ---------------------------------------------------------------------------
__global__ __launch_bounds__(256) void dft4_inv_kernel(
    float* __restrict__ Yr, float* __restrict__ Yi) {
  size_t idx = (size_t)blockIdx.x * 256 + threadIdx.x;
  int n = (int)(idx & (N_SEQ - 1));
  size_t rest = idx >> 12;
  int d = (int)(rest % BS);
  int b = (int)(rest / BS);
  size_t base = ((size_t)(b * C_TOT + d)) * N_SEQ + n;
  const size_t S = (size_t)BS * N_SEQ;
  float z0r = Yr[base],         z0i = Yi[base];
  float z1r = Yr[base + S],     z1i = Yi[base + S];
  float z2r = Yr[base + 2 * S], z2i = Yi[base + 2 * S];
  float z3r = Yr[base + 3 * S], z3i = Yi[base + 3 * S];
  const float s = 1.0f / 128.0f;
  float v0r = (z0r + z1r + z2r + z3r) * s;
  float v0i = (z0i + z1i + z2i + z3i) * s;
  float v1r = (z0r - z1i - z2r + z3i) * s;
  float v1i = (z0i + z1r - z2i - z3r) * s;
  float v2r = (z0r - z1r + z2r - z3r) * s;
  float v2i = (z0i - z1i + z2i - z3i) * s;
  float v3r = (z0r + z1i - z2r - z3i) * s;
  float v3i = (z0i - z1r - z2i + z3r) * s;
  Yr[base]         = v0r; Yi[base]         = v0i;
  Yr[base + S]     = v1r; Yi[base + S]     = v1i;
  Yr[base + 2 * S] = v2r; Yi[base + 2 * S] = v2i;
  Yr[base + 3 * S] = v3r; Yi[base + 3 * S] = v3i;
}

// ---------------------------------------------------------------------------
// Stage 5: inverse FFT along seq axis (unnormalized), take real part,
// write out (b,n,c). One workgroup per (b,c) column.
// ---------------------------------------------------------------------------
__global__ __launch_bounds__(256) void fft_inv_kernel(
    const float* __restrict__ Yr, const float* __restrict__ Yi,
    float* __restrict__ out) {
  __shared__ float2 bufA[N_SEQ];
  __shared__ float2 bufB[N_SEQ];
  const int wg = blockIdx.x;
  const int b = wg / C_TOT, c = wg % C_TOT;
  const float* yr = Yr + (size_t)wg * N_SEQ;
  const float* yi = Yi + (size_t)wg * N_SEQ;
  const int t = threadIdx.x;
#pragma unroll
  for (int m = 0; m < 16; m++) {
    int n = t + m * 256;
    bufA[n] = make_float2(yr[n], yi[n]);
  }
  __syncthreads();
  float2* res = stockham4096(bufA, bufB, t, +1.0f);
  float* op = out + (size_t)b * N_SEQ * C_TOT + c;
#pragma unroll
  for (int m = 0; m < 16; m++) {
    int n = t + m * 256;
    op[(size_t)n * C_TOT] = res[n].x;
  }
}

// ---------------------------------------------------------------------------
extern "C" void kernel_launch(void* const* d_in, const int* in_sizes, int n_in,
                              void* d_out, int out_size, void* d_ws, size_t ws_size,
                              hipStream_t stream) {
  const float* x  = (const float*)d_in[0];
  const float* w1 = (const float*)d_in[1];
  const float* b1 = (const float*)d_in[2];
  const float* w2 = (const float*)d_in[3];
  const float* b2 = (const float*)d_in[4];
  float* out = (float*)d_out;

  const size_t plane = (size_t)B_BATCH * C_TOT * N_SEQ;   // 25,165,824 floats
  if (ws_size < 2 * plane * sizeof(float)) return;        // need 201.3 MB scratch
  float* Yr = (float*)d_ws;
  float* Yi = Yr + plane;

  hipLaunchKernelGGL(fft_fwd_kernel, dim3(B_BATCH * C_TOT), dim3(256), 0, stream,
                     x, Yr, Yi);
  hipLaunchKernelGGL(dft4_fwd_kernel, dim3((B_BATCH * BS * N_SEQ) / 256), dim3(256),
                     0, stream, Yr, Yi);
  hipLaunchKernelGGL(einfft_mlp_kernel, dim3(N_SEQ / RT, NBLK, B_BATCH), dim3(BS),
                     0, stream, Yr, Yi, w1, b1, w2, b2);
  hipLaunchKernelGGL(dft4_inv_kernel, dim3((B_BATCH * BS * N_SEQ) / 256), dim3(256),
                     0, stream, Yr, Yi);
  hipLaunchKernelGGL(fft_inv_kernel, dim3(B_BATCH * C_TOT), dim3(256), 0, stream,
                     Yr, Yi, out);
}

// Round 2
// 919.266 us; speedup vs baseline: 2.6377x; 2.6377x over previous
//
#include <hip/hip_runtime.h>
#include <math.h>

#define N_SEQ   4096
#define C_TOT   768
#define NBLK    4
#define BS      192
#define B_BATCH 8
#define LAMBDA  0.01f
#define KTOT    384            // complex-as-real K (=2*BS)
#define APITCH  392            // LDS pitch in bf16 elems (784 B: rows step 4 banks -> 2-way free)

typedef short    bf16x8  __attribute__((ext_vector_type(8)));
typedef short    short4v __attribute__((ext_vector_type(4)));
typedef float    f32x4   __attribute__((ext_vector_type(4)));
typedef unsigned short ushort_t;

__device__ __forceinline__ unsigned short f2bf(float f) {
  unsigned int u = __float_as_uint(f);
  u = (u + 0x7FFFu + ((u >> 16) & 1u)) >> 16;   // RNE
  return (unsigned short)u;
}
__device__ __forceinline__ float b2f(unsigned short h) {
  return __uint_as_float(((unsigned int)h) << 16);
}

// ---------------------------------------------------------------------------
// Stockham radix-2 FFT core (N=4096), 256 threads, ping-pong LDS.
// ---------------------------------------------------------------------------
__device__ __forceinline__ float2* stockham4096(float2* bufA, float2* bufB,
                                                int t, float sign) {
  float2* src = bufA;
  float2* dst = bufB;
  float inv_p = 1.0f;
  for (int p = 1; p < N_SEQ; p <<= 1) {
#pragma unroll
    for (int m = 0; m < 8; m++) {
      int i = t + m * 256;
      int kk = i & (p - 1);
      float2 u = src[i];
      float2 v = src[i + N_SEQ / 2];
      float ang = sign * (float)M_PI * (float)kk * inv_p;
      float sn, cs;
      __sincosf(ang, &sn, &cs);
      float vr = cs * v.x - sn * v.y;
      float vi = cs * v.y + sn * v.x;
      int j = ((i - kk) << 1) + kk;
      dst[j]     = make_float2(u.x + vr, u.y + vi);
      dst[j + p] = make_float2(u.x - vr, u.y - vi);
    }
    __syncthreads();
    float2* tmp = src; src = dst; dst = tmp;
    inv_p *= 0.5f;
  }
  return src;
}

// ---------------------------------------------------------------------------
// Stage 0: build complex-as-real weight matrices, bf16, j-major.
// Bc[layer][kb][j][k]:  k<192: ( j<192 ? W0[k][j] : W1[k][j-192] )
//                       k>=192:( j<192 ? -W1[k-192][j] : W0[k-192][j-192] )
// ---------------------------------------------------------------------------
__global__ __launch_bounds__(256) void prep_kernel(
    const float* __restrict__ w1, const float* __restrict__ w2,
    ushort_t* __restrict__ Bc) {
  int idx = blockIdx.x * 256 + threadIdx.x;        // [0, 2*4*384*384)
  int layer = idx / 589824; int r = idx - layer * 589824;
  int kb = r / 147456;      int r2 = r - kb * 147456;
  int j = r2 / 384;         int k = r2 - j * 384;
  const float* w = layer ? w2 : w1;
  float v;
  if (k < 192) {
    v = (j < 192) ? w[(kb * 192 + k) * 192 + j]
                  : w[((4 + kb) * 192 + k) * 192 + (j - 192)];
  } else {
    int k2 = k - 192;
    v = (j < 192) ? -w[((4 + kb) * 192 + k2) * 192 + j]
                  :  w[(kb * 192 + k2) * 192 + (j - 192)];
  }
  Bc[idx] = f2bf(v);
}

// ---------------------------------------------------------------------------
// Stage 1: forward FFT along seq. x (b,n,c) fp32 -> Fr/Fi (b,c,n) bf16.
// ---------------------------------------------------------------------------
__global__ __launch_bounds__(256) void fft_fwd_kernel(
    const float* __restrict__ x, ushort_t* __restrict__ Fr,
    ushort_t* __restrict__ Fi) {
  __shared__ float2 bufA[N_SEQ];
  __shared__ float2 bufB[N_SEQ];
  const int wg = blockIdx.x;
  const int b = wg / C_TOT, c = wg % C_TOT;
  const float* xp = x + (size_t)b * N_SEQ * C_TOT + c;
  const int t = threadIdx.x;
#pragma unroll
  for (int m = 0; m < 16; m++) {
    int n = t + m * 256;
    bufA[n] = make_float2(xp[(size_t)n * C_TOT], 0.0f);
  }
  __syncthreads();
  float2* res = stockham4096(bufA, bufB, t, -1.0f);
  ushort_t* yr = Fr + (size_t)wg * N_SEQ;
  ushort_t* yi = Fi + (size_t)wg * N_SEQ;
#pragma unroll
  for (int m = 0; m < 16; m++) {
    int n = t + m * 256;
    yr[n] = f2bf(res[n].x);
    yi[n] = f2bf(res[n].y);
  }
}

// ---------------------------------------------------------------------------
// Stage 2: DFT-4 across blocks + 1/128 ortho scale + transpose to GEMM-ready
// layout. Fr/Fi (b,c,n) bf16 -> Zb (b,kb,n, k=384) bf16 (k: [0,192)=re d,
// [192,384)=im d). One wg per (b, kb, 64-n tile).
// ---------------------------------------------------------------------------
__global__ __launch_bounds__(256) void dft4t_kernel(
    const ushort_t* __restrict__ Fr, const ushort_t* __restrict__ Fi,
    ushort_t* __restrict__ Zb) {
  __shared__ ushort_t T[64 * APITCH];
  const int nt = blockIdx.x, kb = blockIdx.y, b = blockIdx.z;
  const int n0 = nt * 64;
  const int lane = threadIdx.x & 63, wave = threadIdx.x >> 6;
  const size_t S = (size_t)BS * N_SEQ;
  const float s = 0.0078125f;                       // 1/128
  for (int dd = 0; dd < 48; dd++) {
    int d = wave * 48 + dd;
    size_t base = ((size_t)(b * C_TOT + d)) * N_SEQ + n0 + lane;
    float y0r = b2f(Fr[base]),         y0i = b2f(Fi[base]);
    float y1r = b2f(Fr[base + S]),     y1i = b2f(Fi[base + S]);
    float y2r = b2f(Fr[base + 2 * S]), y2i = b2f(Fi[base + 2 * S]);
    float y3r = b2f(Fr[base + 3 * S]), y3i = b2f(Fi[base + 3 * S]);
    float zr, zi;
    if (kb == 0)      { zr = y0r + y1r + y2r + y3r; zi = y0i + y1i + y2i + y3i; }
    else if (kb == 1) { zr = y0r + y1i - y2r - y3i; zi = y0i - y1r - y2i + y3r; }
    else if (kb == 2) { zr = y0r - y1r + y2r - y3r; zi = y0i - y1i + y2i - y3i; }
    else              { zr = y0r - y1i - y2r + y3i; zi = y0i + y1r - y2i - y3r; }
    T[lane * APITCH + d]       = f2bf(zr * s);
    T[lane * APITCH + 192 + d] = f2bf(zi * s);
  }
  __syncthreads();
  const size_t obase = ((size_t)((b * 4 + kb) * N_SEQ + n0)) * KTOT;
#pragma unroll
  for (int it = 0; it < 12; it++) {
    int g = it * 256 + threadIdx.x;                 // 16-B granule
    int row = g / 48, c8 = g - row * 48;
    *(bf16x8*)(Zb + obase + (size_t)g * 8) =
        *(const bf16x8*)(&T[row * APITCH + c8 * 8]);
  }
}

// ---------------------------------------------------------------------------
// Stage 3: MFMA 2-layer complex MLP. One wg = (b, kb, 64-n tile), 4 waves.
// Wave w owns output cols [w*96, w*96+96). A (64x384) staged in LDS;
// B fragments loaded directly from L2-resident Bc; H reuses the A buffer.
// ---------------------------------------------------------------------------
__global__ __launch_bounds__(256, 3) void mlp_kernel(
    const ushort_t* __restrict__ Zb,
    const ushort_t* __restrict__ Bc,       // [2][4][384][384] j-major
    const float* __restrict__ b1g, const float* __restrict__ b2g,
    ushort_t* __restrict__ Or, ushort_t* __restrict__ Oi) {
  __shared__ ushort_t Abuf[64 * APITCH];
  const int nt = blockIdx.x, kb = blockIdx.y, b = blockIdx.z;
  const int n0 = nt * 64;
  const int tid = threadIdx.x;
  const int lane = tid & 63, wave = tid >> 6;
  const int fr = lane & 15, fg = lane >> 4;
  const int col0 = wave * 96;

  // ---- stage A tile (contiguous 48 KB) into padded LDS ----
  {
    const ushort_t* gsrc = Zb + ((size_t)((b * 4 + kb) * N_SEQ + n0)) * KTOT;
#pragma unroll
    for (int it = 0; it < 12; it++) {
      int g = it * 256 + tid;
      int row = g / 48, c8 = g - row * 48;
      *(bf16x8*)(&Abuf[row * APITCH + c8 * 8]) = *(const bf16x8*)(gsrc + (size_t)g * 8);
    }
  }
  __syncthreads();

  const ushort_t* B1 = Bc + (size_t)kb * KTOT * KTOT;
  const ushort_t* B2 = Bc + (size_t)(4 + kb) * KTOT * KTOT;

  f32x4 acc[4][6];
#pragma unroll
  for (int rt = 0; rt < 4; rt++)
#pragma unroll
    for (int ct = 0; ct < 6; ct++) acc[rt][ct] = 0.0f;

  // ---- layer 1: acc = A * B1 ----
  for (int kc = 0; kc < 12; kc++) {
    bf16x8 bfr[6];
    const ushort_t* bp = B1 + (size_t)(col0 + fr) * KTOT + kc * 32 + fg * 8;
#pragma unroll
    for (int ct = 0; ct < 6; ct++) bfr[ct] = *(const bf16x8*)(bp + ct * 16 * KTOT);
    bf16x8 afr[4];
#pragma unroll
    for (int rt = 0; rt < 4; rt++)
      afr[rt] = *(const bf16x8*)(&Abuf[(rt * 16 + fr) * APITCH + kc * 32 + fg * 8]);
#pragma unroll
    for (int rt = 0; rt < 4; rt++)
#pragma unroll
      for (int ct = 0; ct < 6; ct++)
        acc[rt][ct] = __builtin_amdgcn_mfma_f32_16x16x32_bf16(
            afr[rt], bfr[ct], acc[rt][ct], 0, 0, 0);
  }

  // ---- H = relu(acc + b1) -> back into Abuf (bf16) ----
  __syncthreads();   // all waves done reading A
#pragma unroll
  for (int ct = 0; ct < 6; ct++) {
    int j = col0 + ct * 16 + fr;
    float bias = (j < 192) ? b1g[kb * 192 + j] : b1g[768 + kb * 192 + (j - 192)];
#pragma unroll
    for (int rt = 0; rt < 4; rt++)
#pragma unroll
      for (int reg = 0; reg < 4; reg++) {
        float v = acc[rt][ct][reg] + bias;
        v = fmaxf(v, 0.0f);
        Abuf[(rt * 16 + fg * 4 + reg) * APITCH + j] = f2bf(v);
      }
  }
  __syncthreads();

#pragma unroll
  for (int rt = 0; rt < 4; rt++)
#pragma unroll
    for (int ct = 0; ct < 6; ct++) acc[rt][ct] = 0.0f;

  // ---- layer 2: acc = H * B2 ----
  for (int kc = 0; kc < 12; kc++) {
    bf16x8 bfr[6];
    const ushort_t* bp = B2 + (size_t)(col0 + fr) * KTOT + kc * 32 + fg * 8;
#pragma unroll
    for (int ct = 0; ct < 6; ct++) bfr[ct] = *(const bf16x8*)(bp + ct * 16 * KTOT);
    bf16x8 afr[4];
#pragma unroll
    for (int rt = 0; rt < 4; rt++)
      afr[rt] = *(const bf16x8*)(&Abuf[(rt * 16 + fr) * APITCH + kc * 32 + fg * 8]);
#pragma unroll
    for (int rt = 0; rt < 4; rt++)
#pragma unroll
      for (int ct = 0; ct < 6; ct++)
        acc[rt][ct] = __builtin_amdgcn_mfma_f32_16x16x32_bf16(
            afr[rt], bfr[ct], acc[rt][ct], 0, 0, 0);
  }

  // ---- epilogue: bias + softshrink -> bf16 planes (b,c,n) ----
#pragma unroll
  for (int ct = 0; ct < 6; ct++) {
    int j = col0 + ct * 16 + fr;
    float bias;
    ushort_t* plane;
    if (j < 192) {
      bias = b2g[kb * 192 + j];
      plane = Or + ((size_t)(b * C_TOT + kb * 192 + j)) * N_SEQ;
    } else {
      bias = b2g[768 + kb * 192 + (j - 192)];
      plane = Oi + ((size_t)(b * C_TOT + kb * 192 + (j - 192))) * N_SEQ;
    }
#pragma unroll
    for (int rt = 0; rt < 4; rt++) {
      short4v pk;
#pragma unroll
      for (int reg = 0; reg < 4; reg++) {
        float v = acc[rt][ct][reg] + bias;
        v = (v > LAMBDA) ? (v - LAMBDA) : ((v < -LAMBDA) ? (v + LAMBDA) : 0.0f);
        pk[reg] = (short)f2bf(v);
      }
      *(short4v*)(plane + n0 + rt * 16 + fg * 4) = pk;
    }
  }
}

// ---------------------------------------------------------------------------
// Stage 4: inverse DFT-4 across blocks, in-place bf16, scale 1/128.
// ---------------------------------------------------------------------------
__global__ __launch_bounds__(256) void dft4_inv_kernel(
    ushort_t* __restrict__ Or, ushort_t* __restrict__ Oi) {
  size_t idx = (size_t)blockIdx.x * 256 + threadIdx.x;
  int n = (int)(idx & (N_SEQ - 1));
  size_t rest = idx >> 12;
  int d = (int)(rest % BS);
  int b = (int)(rest / BS);
  size_t base = ((size_t)(b * C_TOT + d)) * N_SEQ + n;
  const size_t S = (size_t)BS * N_SEQ;
  float z0r = b2f(Or[base]),         z0i = b2f(Oi[base]);
  float z1r = b2f(Or[base + S]),     z1i = b2f(Oi[base + S]);
  float z2r = b2f(Or[base + 2 * S]), z2i = b2f(Oi[base + 2 * S]);
  float z3r = b2f(Or[base + 3 * S]), z3i = b2f(Oi[base + 3 * S]);
  const float s = 1.0f / 128.0f;
  float v0r = (z0r + z1r + z2r + z3r) * s;
  float v0i = (z0i + z1i + z2i + z3i) * s;
  float v1r = (z0r - z1i - z2r + z3i) * s;
  float v1i = (z0i + z1r - z2i - z3r) * s;
  float v2r = (z0r - z1r + z2r - z3r) * s;
  float v2i = (z0i - z1i + z2i - z3i) * s;
  float v3r = (z0r + z1i - z2r - z3i) * s;
  float v3i = (z0i - z1r - z2i + z3r) * s;
  Or[base]         = f2bf(v0r); Oi[base]         = f2bf(v0i);
  Or[base + S]     = f2bf(v1r); Oi[base + S]     = f2bf(v1i);
  Or[base + 2 * S] = f2bf(v2r); Oi[base + 2 * S] = f2bf(v2i);
  Or[base + 3 * S] = f2bf(v3r); Oi[base + 3 * S] = f2bf(v3i);
}

// ---------------------------------------------------------------------------
// Stage 5: inverse FFT along seq (unnormalized), real part -> out (b,n,c) fp32.
// ---------------------------------------------------------------------------
__global__ __launch_bounds__(256) void fft_inv_kernel(
    const ushort_t* __restrict__ Or, const ushort_t* __restrict__ Oi,
    float* __restrict__ out) {
  __shared__ float2 bufA[N_SEQ];
  __shared__ float2 bufB[N_SEQ];
  const int wg = blockIdx.x;
  const int b = wg / C_TOT, c = wg % C_TOT;
  const ushort_t* yr = Or + (size_t)wg * N_SEQ;
  const ushort_t* yi = Oi + (size_t)wg * N_SEQ;
  const int t = threadIdx.x;
#pragma unroll
  for (int m = 0; m < 16; m++) {
    int n = t + m * 256;
    bufA[n] = make_float2(b2f(yr[n]), b2f(yi[n]));
  }
  __syncthreads();
  float2* res = stockham4096(bufA, bufB, t, +1.0f);
  float* op = out + (size_t)b * N_SEQ * C_TOT + c;
#pragma unroll
  for (int m = 0; m < 16; m++) {
    int n = t + m * 256;
    op[(size_t)n * C_TOT] = res[n].x;
  }
}

// ---------------------------------------------------------------------------
extern "C" void kernel_launch(void* const* d_in, const int* in_sizes, int n_in,
                              void* d_out, int out_size, void* d_ws, size_t ws_size,
                              hipStream_t stream) {
  const float* x  = (const float*)d_in[0];
  const float* w1 = (const float*)d_in[1];
  const float* b1 = (const float*)d_in[2];
  const float* w2 = (const float*)d_in[3];
  const float* b2 = (const float*)d_in[4];
  float* out = (float*)d_out;

  const size_t P = (size_t)B_BATCH * C_TOT * N_SEQ;       // 25,165,824
  // ws layout (ushorts): Fr[P] | Fi[P] | Zb[2P] | Bc[2*589824]
  const size_t need = (4 * P + 2 * 589824) * sizeof(ushort_t);  // 203,685,888 B
  if (ws_size < need) return;
  ushort_t* Fr = (ushort_t*)d_ws;
  ushort_t* Fi = Fr + P;
  ushort_t* Zb = Fr + 2 * P;
  ushort_t* Bc = Fr + 4 * P;

  hipLaunchKernelGGL(prep_kernel, dim3(4608), dim3(256), 0, stream, w1, w2, Bc);
  hipLaunchKernelGGL(fft_fwd_kernel, dim3(B_BATCH * C_TOT), dim3(256), 0, stream,
                     x, Fr, Fi);
  hipLaunchKernelGGL(dft4t_kernel, dim3(N_SEQ / 64, NBLK, B_BATCH), dim3(256),
                     0, stream, Fr, Fi, Zb);
  hipLaunchKernelGGL(mlp_kernel, dim3(N_SEQ / 64, NBLK, B_BATCH), dim3(256),
                     0, stream, Zb, Bc, b1, b2, Fr, Fi);   // output overwrites Fr/Fi
  hipLaunchKernelGGL(dft4_inv_kernel, dim3((B_BATCH * BS * N_SEQ) / 256), dim3(256),
                     0, stream, Fr, Fi);
  hipLaunchKernelGGL(fft_inv_kernel, dim3(B_BATCH * C_TOT), dim3(256), 0, stream,
                     Fr, Fi, out);
}

// Round 3
// 636.839 us; speedup vs baseline: 3.8074x; 1.4435x over previous
//
#include <hip/hip_runtime.h>
#include <math.h>

#define N_SEQ   4096
#define C_TOT   768
#define NBLK    4
#define BS      192
#define B_BATCH 8
#define LAMBDA  0.01f
#define KTOT    384            // complex-as-real K (=2*BS)
#define APITCH  392            // LDS pitch in bf16 elems for MLP A-tile

typedef short    bf16x8  __attribute__((ext_vector_type(8)));
typedef short    short4v __attribute__((ext_vector_type(4)));
typedef float    f32x4   __attribute__((ext_vector_type(4)));
typedef unsigned short ushort_t;

__device__ __forceinline__ unsigned short f2bf(float f) {
  unsigned int u = __float_as_uint(f);
  u = (u + 0x7FFFu + ((u >> 16) & 1u)) >> 16;   // RNE
  return (unsigned short)u;
}
__device__ __forceinline__ float b2f(unsigned short h) {
  return __uint_as_float(((unsigned int)h) << 16);
}

// ---------------------------------------------------------------------------
// Stockham radix-2 FFT core (N=4096), SoA re/im LDS (<=2-way bank aliasing),
// 256 threads, ping-pong. 12 stages (even) => result lands back in Ar/Ai.
// sign = -1 forward, +1 inverse; unnormalized.
// ---------------------------------------------------------------------------
__device__ __forceinline__ void stockham_soa(float* Ar, float* Ai,
                                             float* Br, float* Bi,
                                             int t, float sign) {
  float *sr = Ar, *si = Ai, *dr = Br, *di = Bi;
  float inv_p = 1.0f;
  for (int s = 0; s < 12; s++) {
    int p = 1 << s;
#pragma unroll
    for (int m = 0; m < 8; m++) {
      int i = t + m * 256;
      int kk = i & (p - 1);
      float ur = sr[i],        ui = si[i];
      float vr = sr[i + 2048], vi = si[i + 2048];
      float ang = sign * (float)M_PI * (float)kk * inv_p;
      float sn, cs;
      __sincosf(ang, &sn, &cs);
      float tr = cs * vr - sn * vi;
      float ti = cs * vi + sn * vr;
      int j = ((i - kk) << 1) + kk;
      dr[j]     = ur + tr;  di[j]     = ui + ti;
      dr[j + p] = ur - tr;  di[j + p] = ui - ti;
    }
    __syncthreads();
    float* tp;
    tp = sr; sr = dr; dr = tp;
    tp = si; si = di; di = tp;
    inv_p *= 0.5f;
  }
}

// ---------------------------------------------------------------------------
// Generic 64x64-tile transpose: src (B x R x C) -> dst (B x C x R), fp32.
// ---------------------------------------------------------------------------
__global__ __launch_bounds__(256) void transpose_kernel(
    const float* __restrict__ src, float* __restrict__ dst, int R, int C) {
  __shared__ float tile[64][65];
  const int c0 = blockIdx.x * 64, r0 = blockIdx.y * 64, b = blockIdx.z;
  const int tid = threadIdx.x;
#pragma unroll
  for (int it = 0; it < 4; it++) {
    int g = it * 256 + tid;            // 1024 float4 granules
    int r = g >> 4, q = g & 15;
    float4 v = *(const float4*)(src + ((size_t)b * R + r0 + r) * C + c0 + q * 4);
    tile[q * 4 + 0][r] = v.x;
    tile[q * 4 + 1][r] = v.y;
    tile[q * 4 + 2][r] = v.z;
    tile[q * 4 + 3][r] = v.w;
  }
  __syncthreads();
#pragma unroll
  for (int it = 0; it < 4; it++) {
    int g = it * 256 + tid;
    int c = g >> 4, w = g & 15;
    float4 v = make_float4(tile[c][w * 4 + 0], tile[c][w * 4 + 1],
                           tile[c][w * 4 + 2], tile[c][w * 4 + 3]);
    *(float4*)(dst + ((size_t)b * C + c0 + c) * R + r0 + w * 4) = v;
  }
}

// ---------------------------------------------------------------------------
// Stage 0: build complex-as-real weight matrices, bf16, j-major.
// ---------------------------------------------------------------------------
__global__ __launch_bounds__(256) void prep_kernel(
    const float* __restrict__ w1, const float* __restrict__ w2,
    ushort_t* __restrict__ Bc) {
  int idx = blockIdx.x * 256 + threadIdx.x;        // [0, 2*4*384*384)
  int layer = idx / 589824; int r = idx - layer * 589824;
  int kb = r / 147456;      int r2 = r - kb * 147456;
  int j = r2 / 384;         int k = r2 - j * 384;
  const float* w = layer ? w2 : w1;
  float v;
  if (k < 192) {
    v = (j < 192) ? w[(kb * 192 + k) * 192 + j]
                  : w[((4 + kb) * 192 + k) * 192 + (j - 192)];
  } else {
    int k2 = k - 192;
    v = (j < 192) ? -w[((4 + kb) * 192 + k2) * 192 + j]
                  :  w[(kb * 192 + k2) * 192 + (j - 192)];
  }
  Bc[idx] = f2bf(v);
}

// ---------------------------------------------------------------------------
// Stage 1: forward FFT, two real columns packed per workgroup.
// xT (b,c,n) fp32 (contiguous rows) -> Fr/Fi (b,c,n) bf16.
// W = x_{c1} + i*x_{c2};  X1 = (W[k]+conj(W[-k]))/2, X2 = -i(W[k]-conj(W[-k]))/2.
// ---------------------------------------------------------------------------
__global__ __launch_bounds__(256) void fft_fwd_kernel(
    const float* __restrict__ xT, ushort_t* __restrict__ Fr,
    ushort_t* __restrict__ Fi) {
  __shared__ float Ar[N_SEQ], Ai[N_SEQ], Br[N_SEQ], Bi[N_SEQ];
  const int q = blockIdx.x, b = blockIdx.y;        // q in [0,384)
  const int c1 = 2 * q;
  const int t = threadIdx.x;
  const float* p1 = xT + ((size_t)b * C_TOT + c1) * N_SEQ;
  const float* p2 = p1 + N_SEQ;
#pragma unroll
  for (int m = 0; m < 4; m++) {
    int i4 = m * 256 + t;
    *(float4*)&Ar[i4 * 4] = ((const float4*)p1)[i4];
    *(float4*)&Ai[i4 * 4] = ((const float4*)p2)[i4];
  }
  __syncthreads();
  stockham_soa(Ar, Ai, Br, Bi, t, -1.0f);
  // result in Ar/Ai; unpack the two real-column spectra
  ushort_t* fr1 = Fr + ((size_t)b * C_TOT + c1) * N_SEQ;
  ushort_t* fi1 = Fi + ((size_t)b * C_TOT + c1) * N_SEQ;
#pragma unroll
  for (int m = 0; m < 16; m++) {
    int k = t + m * 256;
    int km = (N_SEQ - k) & (N_SEQ - 1);
    float a = Ar[k], bb = Ai[k], c = Ar[km], d = Ai[km];
    fr1[k]         = f2bf(0.5f * (a + c));    // X1.re
    fi1[k]         = f2bf(0.5f * (bb - d));   // X1.im
    fr1[N_SEQ + k] = f2bf(0.5f * (bb + d));   // X2.re
    fi1[N_SEQ + k] = f2bf(0.5f * (c - a));    // X2.im
  }
}

// ---------------------------------------------------------------------------
// Stage 2: DFT-4 across blocks + 1/128 ortho scale + transpose to GEMM-ready
// layout. Fr/Fi (b,c,n) bf16 -> Zb (b,kb,n,k=384) bf16.
// ---------------------------------------------------------------------------
__global__ __launch_bounds__(256) void dft4t_kernel(
    const ushort_t* __restrict__ Fr, const ushort_t* __restrict__ Fi,
    ushort_t* __restrict__ Zb) {
  __shared__ ushort_t T[64 * APITCH];
  const int nt = blockIdx.x, kb = blockIdx.y, b = blockIdx.z;
  const int n0 = nt * 64;
  const int lane = threadIdx.x & 63, wave = threadIdx.x >> 6;
  const size_t S = (size_t)BS * N_SEQ;
  const float s = 0.0078125f;                       // 1/128
  for (int dd = 0; dd < 48; dd++) {
    int d = wave * 48 + dd;
    size_t base = ((size_t)(b * C_TOT + d)) * N_SEQ + n0 + lane;
    float y0r = b2f(Fr[base]),         y0i = b2f(Fi[base]);
    float y1r = b2f(Fr[base + S]),     y1i = b2f(Fi[base + S]);
    float y2r = b2f(Fr[base + 2 * S]), y2i = b2f(Fi[base + 2 * S]);
    float y3r = b2f(Fr[base + 3 * S]), y3i = b2f(Fi[base + 3 * S]);
    float zr, zi;
    if (kb == 0)      { zr = y0r + y1r + y2r + y3r; zi = y0i + y1i + y2i + y3i; }
    else if (kb == 1) { zr = y0r + y1i - y2r - y3i; zi = y0i - y1r - y2i + y3r; }
    else if (kb == 2) { zr = y0r - y1r + y2r - y3r; zi = y0i - y1i + y2i - y3i; }
    else              { zr = y0r - y1i - y2r + y3i; zi = y0i + y1r - y2i - y3r; }
    T[lane * APITCH + d]       = f2bf(zr * s);
    T[lane * APITCH + 192 + d] = f2bf(zi * s);
  }
  __syncthreads();
  const size_t obase = ((size_t)((b * 4 + kb) * N_SEQ + n0)) * KTOT;
#pragma unroll
  for (int it = 0; it < 12; it++) {
    int g = it * 256 + threadIdx.x;                 // 16-B granule
    int row = g / 48, c8 = g - row * 48;
    *(bf16x8*)(Zb + obase + (size_t)g * 8) =
        *(const bf16x8*)(&T[row * APITCH + c8 * 8]);
  }
}

// ---------------------------------------------------------------------------
// Stage 3: MFMA 2-layer complex MLP (unchanged from round 2).
// ---------------------------------------------------------------------------
__global__ __launch_bounds__(256, 3) void mlp_kernel(
    const ushort_t* __restrict__ Zb,
    const ushort_t* __restrict__ Bc,       // [2][4][384][384] j-major
    const float* __restrict__ b1g, const float* __restrict__ b2g,
    ushort_t* __restrict__ Or, ushort_t* __restrict__ Oi) {
  __shared__ ushort_t Abuf[64 * APITCH];
  const int nt = blockIdx.x, kb = blockIdx.y, b = blockIdx.z;
  const int n0 = nt * 64;
  const int tid = threadIdx.x;
  const int lane = tid & 63, wave = tid >> 6;
  const int fr = lane & 15, fg = lane >> 4;
  const int col0 = wave * 96;

  {
    const ushort_t* gsrc = Zb + ((size_t)((b * 4 + kb) * N_SEQ + n0)) * KTOT;
#pragma unroll
    for (int it = 0; it < 12; it++) {
      int g = it * 256 + tid;
      int row = g / 48, c8 = g - row * 48;
      *(bf16x8*)(&Abuf[row * APITCH + c8 * 8]) = *(const bf16x8*)(gsrc + (size_t)g * 8);
    }
  }
  __syncthreads();

  const ushort_t* B1 = Bc + (size_t)kb * KTOT * KTOT;
  const ushort_t* B2 = Bc + (size_t)(4 + kb) * KTOT * KTOT;

  f32x4 acc[4][6];
#pragma unroll
  for (int rt = 0; rt < 4; rt++)
#pragma unroll
    for (int ct = 0; ct < 6; ct++) acc[rt][ct] = 0.0f;

  for (int kc = 0; kc < 12; kc++) {
    bf16x8 bfr[6];
    const ushort_t* bp = B1 + (size_t)(col0 + fr) * KTOT + kc * 32 + fg * 8;
#pragma unroll
    for (int ct = 0; ct < 6; ct++) bfr[ct] = *(const bf16x8*)(bp + ct * 16 * KTOT);
    bf16x8 afr[4];
#pragma unroll
    for (int rt = 0; rt < 4; rt++)
      afr[rt] = *(const bf16x8*)(&Abuf[(rt * 16 + fr) * APITCH + kc * 32 + fg * 8]);
#pragma unroll
    for (int rt = 0; rt < 4; rt++)
#pragma unroll
      for (int ct = 0; ct < 6; ct++)
        acc[rt][ct] = __builtin_amdgcn_mfma_f32_16x16x32_bf16(
            afr[rt], bfr[ct], acc[rt][ct], 0, 0, 0);
  }

  __syncthreads();
#pragma unroll
  for (int ct = 0; ct < 6; ct++) {
    int j = col0 + ct * 16 + fr;
    float bias = (j < 192) ? b1g[kb * 192 + j] : b1g[768 + kb * 192 + (j - 192)];
#pragma unroll
    for (int rt = 0; rt < 4; rt++)
#pragma unroll
      for (int reg = 0; reg < 4; reg++) {
        float v = acc[rt][ct][reg] + bias;
        v = fmaxf(v, 0.0f);
        Abuf[(rt * 16 + fg * 4 + reg) * APITCH + j] = f2bf(v);
      }
  }
  __syncthreads();

#pragma unroll
  for (int rt = 0; rt < 4; rt++)
#pragma unroll
    for (int ct = 0; ct < 6; ct++) acc[rt][ct] = 0.0f;

  for (int kc = 0; kc < 12; kc++) {
    bf16x8 bfr[6];
    const ushort_t* bp = B2 + (size_t)(col0 + fr) * KTOT + kc * 32 + fg * 8;
#pragma unroll
    for (int ct = 0; ct < 6; ct++) bfr[ct] = *(const bf16x8*)(bp + ct * 16 * KTOT);
    bf16x8 afr[4];
#pragma unroll
    for (int rt = 0; rt < 4; rt++)
      afr[rt] = *(const bf16x8*)(&Abuf[(rt * 16 + fr) * APITCH + kc * 32 + fg * 8]);
#pragma unroll
    for (int rt = 0; rt < 4; rt++)
#pragma unroll
      for (int ct = 0; ct < 6; ct++)
        acc[rt][ct] = __builtin_amdgcn_mfma_f32_16x16x32_bf16(
            afr[rt], bfr[ct], acc[rt][ct], 0, 0, 0);
  }

#pragma unroll
  for (int ct = 0; ct < 6; ct++) {
    int j = col0 + ct * 16 + fr;
    float bias;
    ushort_t* plane;
    if (j < 192) {
      bias = b2g[kb * 192 + j];
      plane = Or + ((size_t)(b * C_TOT + kb * 192 + j)) * N_SEQ;
    } else {
      bias = b2g[768 + kb * 192 + (j - 192)];
      plane = Oi + ((size_t)(b * C_TOT + kb * 192 + (j - 192))) * N_SEQ;
    }
#pragma unroll
    for (int rt = 0; rt < 4; rt++) {
      short4v pk;
#pragma unroll
      for (int reg = 0; reg < 4; reg++) {
        float v = acc[rt][ct][reg] + bias;
        v = (v > LAMBDA) ? (v - LAMBDA) : ((v < -LAMBDA) ? (v + LAMBDA) : 0.0f);
        pk[reg] = (short)f2bf(v);
      }
      *(short4v*)(plane + n0 + rt * 16 + fg * 4) = pk;
    }
  }
}

// ---------------------------------------------------------------------------
// Stage 4: inverse DFT-4 across blocks, in-place bf16, scale 1/128.
// ---------------------------------------------------------------------------
__global__ __launch_bounds__(256) void dft4_inv_kernel(
    ushort_t* __restrict__ Or, ushort_t* __restrict__ Oi) {
  size_t idx = (size_t)blockIdx.x * 256 + threadIdx.x;
  int n = (int)(idx & (N_SEQ - 1));
  size_t rest = idx >> 12;
  int d = (int)(rest % BS);
  int b = (int)(rest / BS);
  size_t base = ((size_t)(b * C_TOT + d)) * N_SEQ + n;
  const size_t S = (size_t)BS * N_SEQ;
  float z0r = b2f(Or[base]),         z0i = b2f(Oi[base]);
  float z1r = b2f(Or[base + S]),     z1i = b2f(Oi[base + S]);
  float z2r = b2f(Or[base + 2 * S]), z2i = b2f(Oi[base + 2 * S]);
  float z3r = b2f(Or[base + 3 * S]), z3i = b2f(Oi[base + 3 * S]);
  const float s = 1.0f / 128.0f;
  float v0r = (z0r + z1r + z2r + z3r) * s;
  float v0i = (z0i + z1i + z2i + z3i) * s;
  float v1r = (z0r - z1i - z2r + z3i) * s;
  float v1i = (z0i + z1r - z2i - z3r) * s;
  float v2r = (z0r - z1r + z2r - z3r) * s;
  float v2i = (z0i - z1i + z2i - z3i) * s;
  float v3r = (z0r + z1i - z2r - z3i) * s;
  float v3i = (z0i - z1r - z2i + z3r) * s;
  Or[base]         = f2bf(v0r); Oi[base]         = f2bf(v0i);
  Or[base + S]     = f2bf(v1r); Oi[base + S]     = f2bf(v1i);
  Or[base + 2 * S] = f2bf(v2r); Oi[base + 2 * S] = f2bf(v2i);
  Or[base + 3 * S] = f2bf(v3r); Oi[base + 3 * S] = f2bf(v3i);
}

// ---------------------------------------------------------------------------
// Stage 5: inverse FFT, two columns per workgroup via Hermitian projection:
// Zh[k] = (Z[k]+conj(Z[-k]))/2  =>  IFFT(Zh) = Re(IFFT(Z)) (real).
// W = Zh1 + i*Zh2; one IFFT gives y1 = Re, y2 = Im. Writes yT (b,c,n) fp32.
// ---------------------------------------------------------------------------
__global__ __launch_bounds__(256) void fft_inv_kernel(
    const ushort_t* __restrict__ Or, const ushort_t* __restrict__ Oi,
    float* __restrict__ yT) {
  __shared__ float Ar[N_SEQ], Ai[N_SEQ], Br[N_SEQ], Bi[N_SEQ];
  const int q = blockIdx.x, b = blockIdx.y;
  const int c1 = 2 * q;
  const int t = threadIdx.x;
  const ushort_t* zr1 = Or + ((size_t)b * C_TOT + c1) * N_SEQ;
  const ushort_t* zi1 = Oi + ((size_t)b * C_TOT + c1) * N_SEQ;
#pragma unroll
  for (int m = 0; m < 2; m++) {
    int i8 = m * 256 + t;                  // 512 granules of 8 bf16
    bf16x8 a = *(const bf16x8*)(zr1 + i8 * 8);
    bf16x8 bq = *(const bf16x8*)(zi1 + i8 * 8);
    bf16x8 cq = *(const bf16x8*)(zr1 + N_SEQ + i8 * 8);
    bf16x8 dq = *(const bf16x8*)(zi1 + N_SEQ + i8 * 8);
#pragma unroll
    for (int j = 0; j < 8; j++) {
      Ar[i8 * 8 + j] = b2f((unsigned short)a[j]);
      Ai[i8 * 8 + j] = b2f((unsigned short)bq[j]);
      Br[i8 * 8 + j] = b2f((unsigned short)cq[j]);
      Bi[i8 * 8 + j] = b2f((unsigned short)dq[j]);
    }
  }
  __syncthreads();
  // W[k] = Zh1[k] + i*Zh2[k] into registers, then into Ar/Ai
  float wr[16], wi[16];
#pragma unroll
  for (int m = 0; m < 16; m++) {
    int k = t + m * 256;
    int km = (N_SEQ - k) & (N_SEQ - 1);
    float zh1r = 0.5f * (Ar[k] + Ar[km]);
    float zh1i = 0.5f * (Ai[k] - Ai[km]);
    float zh2r = 0.5f * (Br[k] + Br[km]);
    float zh2i = 0.5f * (Bi[k] - Bi[km]);
    wr[m] = zh1r - zh2i;
    wi[m] = zh1i + zh2r;
  }
  __syncthreads();
#pragma unroll
  for (int m = 0; m < 16; m++) {
    int k = t + m * 256;
    Ar[k] = wr[m];
    Ai[k] = wi[m];
  }
  __syncthreads();
  stockham_soa(Ar, Ai, Br, Bi, t, +1.0f);
  // result in Ar/Ai: y_{c1} = Re = Ar, y_{c2} = Im = Ai
  float* y1 = yT + ((size_t)b * C_TOT + c1) * N_SEQ;
#pragma unroll
  for (int m = 0; m < 4; m++) {
    int i4 = m * 256 + t;
    *(float4*)(y1 + i4 * 4)         = *(float4*)&Ar[i4 * 4];
    *(float4*)(y1 + N_SEQ + i4 * 4) = *(float4*)&Ai[i4 * 4];
  }
}

// ---------------------------------------------------------------------------
extern "C" void kernel_launch(void* const* d_in, const int* in_sizes, int n_in,
                              void* d_out, int out_size, void* d_ws, size_t ws_size,
                              hipStream_t stream) {
  const float* x  = (const float*)d_in[0];
  const float* w1 = (const float*)d_in[1];
  const float* b1 = (const float*)d_in[2];
  const float* w2 = (const float*)d_in[3];
  const float* b2 = (const float*)d_in[4];
  float* out = (float*)d_out;

  const size_t P = (size_t)B_BATCH * C_TOT * N_SEQ;       // 25,165,824 elems
  // ws layout (bytes):
  //   region A [0, 4P):   xT (P fp32) -> Zb (2P bf16) -> yT (P fp32)  (serial reuse)
  //   region B [4P, 6P):  Fr (P bf16) -> Or
  //   region C [6P, 8P):  Fi (P bf16) -> Oi
  //   Bc at 8P: 2*589824 bf16
  const size_t need = 8 * P + 2 * 589824 * sizeof(ushort_t);  // 203,685,888 B
  if (ws_size < need) return;
  char* base = (char*)d_ws;
  float*    xT = (float*)base;
  ushort_t* Zb = (ushort_t*)base;
  float*    yT = (float*)base;
  ushort_t* Fr = (ushort_t*)(base + 4 * P);
  ushort_t* Fi = (ushort_t*)(base + 6 * P);
  ushort_t* Bc = (ushort_t*)(base + 8 * P);

  hipLaunchKernelGGL(prep_kernel, dim3(4608), dim3(256), 0, stream, w1, w2, Bc);
  // x (b,n,c) -> xT (b,c,n)
  hipLaunchKernelGGL(transpose_kernel, dim3(C_TOT / 64, N_SEQ / 64, B_BATCH),
                     dim3(256), 0, stream, x, xT, N_SEQ, C_TOT);
  hipLaunchKernelGGL(fft_fwd_kernel, dim3(C_TOT / 2, B_BATCH), dim3(256), 0,
                     stream, xT, Fr, Fi);
  hipLaunchKernelGGL(dft4t_kernel, dim3(N_SEQ / 64, NBLK, B_BATCH), dim3(256),
                     0, stream, Fr, Fi, Zb);
  hipLaunchKernelGGL(mlp_kernel, dim3(N_SEQ / 64, NBLK, B_BATCH), dim3(256),
                     0, stream, Zb, Bc, b1, b2, Fr, Fi);   // Or/Oi overwrite Fr/Fi
  hipLaunchKernelGGL(dft4_inv_kernel, dim3((B_BATCH * BS * N_SEQ) / 256), dim3(256),
                     0, stream, Fr, Fi);
  hipLaunchKernelGGL(fft_inv_kernel, dim3(C_TOT / 2, B_BATCH), dim3(256), 0,
                     stream, Fr, Fi, yT);
  // yT (b,c,n) -> out (b,n,c)
  hipLaunchKernelGGL(transpose_kernel, dim3(N_SEQ / 64, C_TOT / 64, B_BATCH),
                     dim3(256), 0, stream, yT, out, C_TOT, N_SEQ);
}

// Round 4
// 496.628 us; speedup vs baseline: 4.8823x; 1.2823x over previous
//
#include <hip/hip_runtime.h>
#include <math.h>

#define N_SEQ   4096
#define C_TOT   768
#define NBLK    4
#define BS      192
#define B_BATCH 8
#define LAMBDA  0.01f
#define KTOT    384            // complex-as-real K (=2*BS)
#define APITCH  392            // LDS pitch in bf16 elems for MLP A-tile
#define SW(x)   ((x) ^ (((x) >> 5) & 31))   // FFT LDS bank swizzle

typedef short    bf16x8  __attribute__((ext_vector_type(8)));
typedef short    short4v __attribute__((ext_vector_type(4)));
typedef float    f32x4   __attribute__((ext_vector_type(4)));
typedef unsigned short ushort_t;

__device__ __forceinline__ unsigned short f2bf(float f) {
  unsigned int u = __float_as_uint(f);
  u = (u + 0x7FFFu + ((u >> 16) & 1u)) >> 16;   // RNE
  return (unsigned short)u;
}
__device__ __forceinline__ float b2f(unsigned short h) {
  return __uint_as_float(((unsigned int)h) << 16);
}

// ---------------------------------------------------------------------------
// Stockham radix-4 FFT core (N=4096 = 4^6), 512 threads, SoA re/im LDS with
// XOR bank swizzle, ping-pong. 6 stages (even) => result back in Ar/Ai.
// Stage: k=i mod p, j=4(i-k)+k; a_q = src[i+q*1024]*w^q, w=exp(sign*i*2pi*k/(4p));
// X0=t0+t2, X2=t0-t2, X1=t1+sign*i*t3, X3=t1-sign*i*t3  (t0=a0+b2, t1=a0-b2,
// t2=b1+b3, t3=b1-b3). Verified against DFT16 factorization.
// ---------------------------------------------------------------------------
__device__ __forceinline__ void stockham_soa4(float* Ar, float* Ai,
                                              float* Br, float* Bi,
                                              int t, float sign) {
  float *sr = Ar, *si = Ai, *dr = Br, *di = Bi;
  float inv_p = 1.0f;
  int p = 1;
#pragma unroll
  for (int s = 0; s < 6; s++) {
#pragma unroll
    for (int m = 0; m < 2; m++) {
      int i = t + m * 512;                 // i in [0, 1024)
      int k = i & (p - 1);
      float a0r = sr[SW(i)],        a0i = si[SW(i)];
      float a1r = sr[SW(i + 1024)], a1i = si[SW(i + 1024)];
      float a2r = sr[SW(i + 2048)], a2i = si[SW(i + 2048)];
      float a3r = sr[SW(i + 3072)], a3i = si[SW(i + 3072)];
      float ang = sign * 1.5707963268f * inv_p * (float)k;   // sign*2pi*k/(4p)
      float s1, c1;
      __sincosf(ang, &s1, &c1);
      float c2 = c1 * c1 - s1 * s1, s2 = 2.0f * c1 * s1;
      float c3 = c1 * c2 - s1 * s2, s3 = c1 * s2 + s1 * c2;
      float b1r = c1 * a1r - s1 * a1i, b1i = c1 * a1i + s1 * a1r;
      float b2r = c2 * a2r - s2 * a2i, b2i = c2 * a2i + s2 * a2r;
      float b3r = c3 * a3r - s3 * a3i, b3i = c3 * a3i + s3 * a3r;
      float t0r = a0r + b2r, t0i = a0i + b2i;
      float t1r = a0r - b2r, t1i = a0i - b2i;
      float t2r = b1r + b3r, t2i = b1i + b3i;
      float t3r = b1r - b3r, t3i = b1i - b3i;
      int j = ((i - k) << 2) + k;
      dr[SW(j)]         = t0r + t2r;        di[SW(j)]         = t0i + t2i;
      dr[SW(j + p)]     = t1r - sign * t3i; di[SW(j + p)]     = t1i + sign * t3r;
      dr[SW(j + 2 * p)] = t0r - t2r;        di[SW(j + 2 * p)] = t0i - t2i;
      dr[SW(j + 3 * p)] = t1r + sign * t3i; di[SW(j + 3 * p)] = t1i - sign * t3r;
    }
    __syncthreads();
    float* tp;
    tp = sr; sr = dr; dr = tp;
    tp = si; si = di; di = tp;
    p <<= 2;
    inv_p *= 0.25f;
  }
}

// ---------------------------------------------------------------------------
// Generic 64x64-tile transpose: src (B x R x C) -> dst (B x C x R), fp32.
// ---------------------------------------------------------------------------
__global__ __launch_bounds__(256) void transpose_kernel(
    const float* __restrict__ src, float* __restrict__ dst, int R, int C) {
  __shared__ float tile[64][65];
  const int c0 = blockIdx.x * 64, r0 = blockIdx.y * 64, b = blockIdx.z;
  const int tid = threadIdx.x;
#pragma unroll
  for (int it = 0; it < 4; it++) {
    int g = it * 256 + tid;            // 1024 float4 granules
    int r = g >> 4, q = g & 15;
    float4 v = *(const float4*)(src + ((size_t)b * R + r0 + r) * C + c0 + q * 4);
    tile[q * 4 + 0][r] = v.x;
    tile[q * 4 + 1][r] = v.y;
    tile[q * 4 + 2][r] = v.z;
    tile[q * 4 + 3][r] = v.w;
  }
  __syncthreads();
#pragma unroll
  for (int it = 0; it < 4; it++) {
    int g = it * 256 + tid;
    int c = g >> 4, w = g & 15;
    float4 v = make_float4(tile[c][w * 4 + 0], tile[c][w * 4 + 1],
                           tile[c][w * 4 + 2], tile[c][w * 4 + 3]);
    *(float4*)(dst + ((size_t)b * C + c0 + c) * R + r0 + w * 4) = v;
  }
}

// ---------------------------------------------------------------------------
// Stage 0: build complex-as-real weights in MFMA fragment-contiguous layout:
// Bc[layer][kb][jc(24)][kc(12)][lane(64)][e(8)], value = Bv[j][k] with
// j = jc*16 + (lane&15), k = kc*32 + (lane>>4)*8 + e.
// Bv: k<192: ( j<192 ? W0[k][j] : W1[k][j-192] )
//     k>=192:( j<192 ? -W1[k-192][j] : W0[k-192][j-192] )
// ---------------------------------------------------------------------------
__global__ __launch_bounds__(256) void prep_kernel(
    const float* __restrict__ w1, const float* __restrict__ w2,
    ushort_t* __restrict__ Bc) {
  int idx = blockIdx.x * 256 + threadIdx.x;        // [0, 2*4*147456)
  int layer = idx / 589824; int r = idx - layer * 589824;
  int kb = r / 147456;      int r2 = r - kb * 147456;
  int jc = r2 / 6144;       int r3 = r2 - jc * 6144;
  int kc = r3 / 512;        int r4 = r3 - kc * 512;
  int lane = r4 >> 3;       int e = r4 & 7;
  int j = jc * 16 + (lane & 15);
  int k = kc * 32 + (lane >> 4) * 8 + e;
  const float* w = layer ? w2 : w1;
  float v;
  if (k < 192) {
    v = (j < 192) ? w[(kb * 192 + k) * 192 + j]
                  : w[((4 + kb) * 192 + k) * 192 + (j - 192)];
  } else {
    int k2 = k - 192;
    v = (j < 192) ? -w[((4 + kb) * 192 + k2) * 192 + j]
                  :  w[(kb * 192 + k2) * 192 + (j - 192)];
  }
  Bc[idx] = f2bf(v);
}

// ---------------------------------------------------------------------------
// Stage 1: forward FFT, two real columns packed per workgroup (512 thr).
// xT (b,c,n) fp32 -> Fr/Fi (b,c,n) bf16.
// W = x_{c1} + i*x_{c2};  X1 = (W[k]+conj(W[-k]))/2, X2 = -i(W[k]-conj(W[-k]))/2.
// ---------------------------------------------------------------------------
__global__ __launch_bounds__(512) void fft_fwd_kernel(
    const float* __restrict__ xT, ushort_t* __restrict__ Fr,
    ushort_t* __restrict__ Fi) {
  __shared__ float Ar[N_SEQ], Ai[N_SEQ], Br[N_SEQ], Bi[N_SEQ];
  const int q = blockIdx.x, b = blockIdx.y;        // q in [0,384)
  const int c1 = 2 * q;
  const int t = threadIdx.x;
  const float* p1 = xT + ((size_t)b * C_TOT + c1) * N_SEQ;
  const float* p2 = p1 + N_SEQ;
#pragma unroll
  for (int m = 0; m < 8; m++) {
    int i = t + m * 512;
    Ar[SW(i)] = p1[i];
    Ai[SW(i)] = p2[i];
  }
  __syncthreads();
  stockham_soa4(Ar, Ai, Br, Bi, t, -1.0f);
  ushort_t* fr1 = Fr + ((size_t)b * C_TOT + c1) * N_SEQ;
  ushort_t* fi1 = Fi + ((size_t)b * C_TOT + c1) * N_SEQ;
#pragma unroll
  for (int m = 0; m < 8; m++) {
    int k = t + m * 512;
    int km = (N_SEQ - k) & (N_SEQ - 1);
    float a = Ar[SW(k)], bb = Ai[SW(k)], c = Ar[SW(km)], d = Ai[SW(km)];
    fr1[k]         = f2bf(0.5f * (a + c));    // X1.re
    fi1[k]         = f2bf(0.5f * (bb - d));   // X1.im
    fr1[N_SEQ + k] = f2bf(0.5f * (bb + d));   // X2.re
    fi1[N_SEQ + k] = f2bf(0.5f * (c - a));    // X2.im
  }
}

// ---------------------------------------------------------------------------
// Stage 2: DFT-4 across blocks + 1/128 ortho scale + transpose to GEMM-ready
// layout. Fr/Fi (b,c,n) bf16 -> Zb (b,kb,n,k=384) bf16.
// ---------------------------------------------------------------------------
__global__ __launch_bounds__(256) void dft4t_kernel(
    const ushort_t* __restrict__ Fr, const ushort_t* __restrict__ Fi,
    ushort_t* __restrict__ Zb) {
  __shared__ ushort_t T[64 * APITCH];
  const int nt = blockIdx.x, kb = blockIdx.y, b = blockIdx.z;
  const int n0 = nt * 64;
  const int lane = threadIdx.x & 63, wave = threadIdx.x >> 6;
  const size_t S = (size_t)BS * N_SEQ;
  const float s = 0.0078125f;                       // 1/128
  for (int dd = 0; dd < 48; dd++) {
    int d = wave * 48 + dd;
    size_t base = ((size_t)(b * C_TOT + d)) * N_SEQ + n0 + lane;
    float y0r = b2f(Fr[base]),         y0i = b2f(Fi[base]);
    float y1r = b2f(Fr[base + S]),     y1i = b2f(Fi[base + S]);
    float y2r = b2f(Fr[base + 2 * S]), y2i = b2f(Fi[base + 2 * S]);
    float y3r = b2f(Fr[base + 3 * S]), y3i = b2f(Fi[base + 3 * S]);
    float zr, zi;
    if (kb == 0)      { zr = y0r + y1r + y2r + y3r; zi = y0i + y1i + y2i + y3i; }
    else if (kb == 1) { zr = y0r + y1i - y2r - y3i; zi = y0i - y1r - y2i + y3r; }
    else if (kb == 2) { zr = y0r - y1r + y2r - y3r; zi = y0i - y1i + y2i - y3i; }
    else              { zr = y0r - y1i - y2r + y3i; zi = y0i + y1r - y2i - y3r; }
    T[lane * APITCH + d]       = f2bf(zr * s);
    T[lane * APITCH + 192 + d] = f2bf(zi * s);
  }
  __syncthreads();
  const size_t obase = ((size_t)((b * 4 + kb) * N_SEQ + n0)) * KTOT;
#pragma unroll
  for (int it = 0; it < 12; it++) {
    int g = it * 256 + threadIdx.x;                 // 16-B granule
    int row = g / 48, c8 = g - row * 48;
    *(bf16x8*)(Zb + obase + (size_t)g * 8) =
        *(const bf16x8*)(&T[row * APITCH + c8 * 8]);
  }
}

// ---------------------------------------------------------------------------
// Stage 3: MFMA 2-layer complex MLP. One wg = (b, kb, 64-n tile), 4 waves.
// Wave w owns output cols [w*96, w*96+96). A in LDS; B fragments are
// CONTIGUOUS 1KB coalesced loads, ping-pong prefetched one kc ahead.
// ---------------------------------------------------------------------------
__global__ __launch_bounds__(256, 2) void mlp_kernel(
    const ushort_t* __restrict__ Zb,
    const ushort_t* __restrict__ Bc,       // fragment-contiguous (see prep)
    const float* __restrict__ b1g, const float* __restrict__ b2g,
    ushort_t* __restrict__ Or, ushort_t* __restrict__ Oi) {
  __shared__ ushort_t Abuf[64 * APITCH];
  const int nt = blockIdx.x, kb = blockIdx.y, b = blockIdx.z;
  const int n0 = nt * 64;
  const int tid = threadIdx.x;
  const int lane = tid & 63, wave = tid >> 6;
  const int fr = lane & 15, fg = lane >> 4;
  const int col0 = wave * 96;

  {
    const ushort_t* gsrc = Zb + ((size_t)((b * 4 + kb) * N_SEQ + n0)) * KTOT;
#pragma unroll
    for (int it = 0; it < 12; it++) {
      int g = it * 256 + tid;
      int row = g / 48, c8 = g - row * 48;
      *(bf16x8*)(&Abuf[row * APITCH + c8 * 8]) = *(const bf16x8*)(gsrc + (size_t)g * 8);
    }
  }
  __syncthreads();

  // per-(layer,kb) fragment bases; wave's jc0 = wave*6, ct step = 12*512
  const ushort_t* B1 = Bc + (size_t)kb * 147456 + (size_t)wave * 36864 +
                       (size_t)lane * 8;
  const ushort_t* B2 = B1 + 589824;

  f32x4 acc[4][6];
  bf16x8 bf0[6], bf1[6], afr[4];

  auto loadB = [&](const ushort_t* Bb, int kc, bf16x8* dst) {
#pragma unroll
    for (int ct = 0; ct < 6; ct++)
      dst[ct] = *(const bf16x8*)(Bb + (size_t)kc * 512 + ct * 6144);
  };
  auto doK = [&](int kc, bf16x8* bw) {
#pragma unroll
    for (int rt = 0; rt < 4; rt++)
      afr[rt] = *(const bf16x8*)(&Abuf[(rt * 16 + fr) * APITCH + kc * 32 + fg * 8]);
#pragma unroll
    for (int rt = 0; rt < 4; rt++)
#pragma unroll
      for (int ct = 0; ct < 6; ct++)
        acc[rt][ct] = __builtin_amdgcn_mfma_f32_16x16x32_bf16(
            afr[rt], bw[ct], acc[rt][ct], 0, 0, 0);
  };

  // ---- layer 1 ----
#pragma unroll
  for (int rt = 0; rt < 4; rt++)
#pragma unroll
    for (int ct = 0; ct < 6; ct++) acc[rt][ct] = 0.0f;
  loadB(B1, 0, bf0);
#pragma unroll
  for (int kc2 = 0; kc2 < 6; kc2++) {
    loadB(B1, 2 * kc2 + 1, bf1);
    doK(2 * kc2, bf0);
    if (kc2 < 5) loadB(B1, 2 * kc2 + 2, bf0);
    doK(2 * kc2 + 1, bf1);
  }

  // ---- H = relu(acc + b1) -> back into Abuf (bf16) ----
  __syncthreads();   // all waves done reading A
#pragma unroll
  for (int ct = 0; ct < 6; ct++) {
    int j = col0 + ct * 16 + fr;
    float bias = (j < 192) ? b1g[kb * 192 + j] : b1g[768 + kb * 192 + (j - 192)];
#pragma unroll
    for (int rt = 0; rt < 4; rt++)
#pragma unroll
      for (int reg = 0; reg < 4; reg++) {
        float v = acc[rt][ct][reg] + bias;
        v = fmaxf(v, 0.0f);
        Abuf[(rt * 16 + fg * 4 + reg) * APITCH + j] = f2bf(v);
      }
  }
  __syncthreads();

  // ---- layer 2 ----
#pragma unroll
  for (int rt = 0; rt < 4; rt++)
#pragma unroll
    for (int ct = 0; ct < 6; ct++) acc[rt][ct] = 0.0f;
  loadB(B2, 0, bf0);
#pragma unroll
  for (int kc2 = 0; kc2 < 6; kc2++) {
    loadB(B2, 2 * kc2 + 1, bf1);
    doK(2 * kc2, bf0);
    if (kc2 < 5) loadB(B2, 2 * kc2 + 2, bf0);
    doK(2 * kc2 + 1, bf1);
  }

  // ---- epilogue: bias + softshrink -> bf16 planes (b,c,n) ----
#pragma unroll
  for (int ct = 0; ct < 6; ct++) {
    int j = col0 + ct * 16 + fr;
    float bias;
    ushort_t* plane;
    if (j < 192) {
      bias = b2g[kb * 192 + j];
      plane = Or + ((size_t)(b * C_TOT + kb * 192 + j)) * N_SEQ;
    } else {
      bias = b2g[768 + kb * 192 + (j - 192)];
      plane = Oi + ((size_t)(b * C_TOT + kb * 192 + (j - 192))) * N_SEQ;
    }
#pragma unroll
    for (int rt = 0; rt < 4; rt++) {
      short4v pk;
#pragma unroll
      for (int reg = 0; reg < 4; reg++) {
        float v = acc[rt][ct][reg] + bias;
        v = (v > LAMBDA) ? (v - LAMBDA) : ((v < -LAMBDA) ? (v + LAMBDA) : 0.0f);
        pk[reg] = (short)f2bf(v);
      }
      *(short4v*)(plane + n0 + rt * 16 + fg * 4) = pk;
    }
  }
}

// ---------------------------------------------------------------------------
// Stage 4: inverse DFT-4 across blocks, in-place bf16, scale 1/128.
// Vectorized: one thread handles 8 consecutive n.
// ---------------------------------------------------------------------------
__global__ __launch_bounds__(256) void dft4_inv_kernel(
    ushort_t* __restrict__ Or, ushort_t* __restrict__ Oi) {
  size_t tid8 = (size_t)blockIdx.x * 256 + threadIdx.x;   // over B*BS*N_SEQ/8
  int n8 = (int)(tid8 & 511);
  size_t rest = tid8 >> 9;
  int d = (int)(rest % BS);
  int b = (int)(rest / BS);
  size_t base = ((size_t)(b * C_TOT + d)) * N_SEQ + (size_t)n8 * 8;
  const size_t S = (size_t)BS * N_SEQ;
  bf16x8 z0r = *(const bf16x8*)(Or + base),         z0i = *(const bf16x8*)(Oi + base);
  bf16x8 z1r = *(const bf16x8*)(Or + base + S),     z1i = *(const bf16x8*)(Oi + base + S);
  bf16x8 z2r = *(const bf16x8*)(Or + base + 2 * S), z2i = *(const bf16x8*)(Oi + base + 2 * S);
  bf16x8 z3r = *(const bf16x8*)(Or + base + 3 * S), z3i = *(const bf16x8*)(Oi + base + 3 * S);
  bf16x8 o0r, o0i, o1r, o1i, o2r, o2i, o3r, o3i;
  const float s = 1.0f / 128.0f;
#pragma unroll
  for (int e = 0; e < 8; e++) {
    float a0r = b2f((unsigned short)z0r[e]), a0i = b2f((unsigned short)z0i[e]);
    float a1r = b2f((unsigned short)z1r[e]), a1i = b2f((unsigned short)z1i[e]);
    float a2r = b2f((unsigned short)z2r[e]), a2i = b2f((unsigned short)z2i[e]);
    float a3r = b2f((unsigned short)z3r[e]), a3i = b2f((unsigned short)z3i[e]);
    o0r[e] = (short)f2bf((a0r + a1r + a2r + a3r) * s);
    o0i[e] = (short)f2bf((a0i + a1i + a2i + a3i) * s);
    o1r[e] = (short)f2bf((a0r - a1i - a2r + a3i) * s);
    o1i[e] = (short)f2bf((a0i + a1r - a2i - a3r) * s);
    o2r[e] = (short)f2bf((a0r - a1r + a2r - a3r) * s);
    o2i[e] = (short)f2bf((a0i - a1i + a2i - a3i) * s);
    o3r[e] = (short)f2bf((a0r + a1i - a2r - a3i) * s);
    o3i[e] = (short)f2bf((a0i - a1r - a2i + a3r) * s);
  }
  *(bf16x8*)(Or + base)         = o0r; *(bf16x8*)(Oi + base)         = o0i;
  *(bf16x8*)(Or + base + S)     = o1r; *(bf16x8*)(Oi + base + S)     = o1i;
  *(bf16x8*)(Or + base + 2 * S) = o2r; *(bf16x8*)(Oi + base + 2 * S) = o2i;
  *(bf16x8*)(Or + base + 3 * S) = o3r; *(bf16x8*)(Oi + base + 3 * S) = o3i;
}

// ---------------------------------------------------------------------------
// Stage 5: inverse FFT (512 thr), two columns per wg via Hermitian projection:
// Zh[k] = (Z[k]+conj(Z[-k]))/2 ; IFFT(Zh) = Re(IFFT(Z)).
// W = Zh1 + i*Zh2; one IFFT gives y1 = Re, y2 = Im. Writes yT (b,c,n) fp32.
// ---------------------------------------------------------------------------
__global__ __launch_bounds__(512) void fft_inv_kernel(
    const ushort_t* __restrict__ Or, const ushort_t* __restrict__ Oi,
    float* __restrict__ yT) {
  __shared__ float Ar[N_SEQ], Ai[N_SEQ], Br[N_SEQ], Bi[N_SEQ];
  const int q = blockIdx.x, b = blockIdx.y;
  const int c1 = 2 * q;
  const int t = threadIdx.x;
  const ushort_t* zr1 = Or + ((size_t)b * C_TOT + c1) * N_SEQ;
  const ushort_t* zi1 = Oi + ((size_t)b * C_TOT + c1) * N_SEQ;
#pragma unroll
  for (int m = 0; m < 8; m++) {
    int i = t + m * 512;
    Ar[SW(i)] = b2f(zr1[i]);
    Ai[SW(i)] = b2f(zi1[i]);
    Br[SW(i)] = b2f(zr1[N_SEQ + i]);
    Bi[SW(i)] = b2f(zi1[N_SEQ + i]);
  }
  __syncthreads();
  float wr[8], wi[8];
#pragma unroll
  for (int m = 0; m < 8; m++) {
    int k = t + m * 512;
    int km = (N_SEQ - k) & (N_SEQ - 1);
    float zh1r = 0.5f * (Ar[SW(k)] + Ar[SW(km)]);
    float zh1i = 0.5f * (Ai[SW(k)] - Ai[SW(km)]);
    float zh2r = 0.5f * (Br[SW(k)] + Br[SW(km)]);
    float zh2i = 0.5f * (Bi[SW(k)] - Bi[SW(km)]);
    wr[m] = zh1r - zh2i;
    wi[m] = zh1i + zh2r;
  }
  __syncthreads();
#pragma unroll
  for (int m = 0; m < 8; m++) {
    int k = t + m * 512;
    Ar[SW(k)] = wr[m];
    Ai[SW(k)] = wi[m];
  }
  __syncthreads();
  stockham_soa4(Ar, Ai, Br, Bi, t, +1.0f);
  float* y1 = yT + ((size_t)b * C_TOT + c1) * N_SEQ;
#pragma unroll
  for (int m = 0; m < 8; m++) {
    int i = t + m * 512;
    y1[i]         = Ar[SW(i)];
    y1[N_SEQ + i] = Ai[SW(i)];
  }
}

// ---------------------------------------------------------------------------
extern "C" void kernel_launch(void* const* d_in, const int* in_sizes, int n_in,
                              void* d_out, int out_size, void* d_ws, size_t ws_size,
                              hipStream_t stream) {
  const float* x  = (const float*)d_in[0];
  const float* w1 = (const float*)d_in[1];
  const float* b1 = (const float*)d_in[2];
  const float* w2 = (const float*)d_in[3];
  const float* b2 = (const float*)d_in[4];
  float* out = (float*)d_out;

  const size_t P = (size_t)B_BATCH * C_TOT * N_SEQ;       // 25,165,824 elems
  // ws layout (bytes):
  //   region A [0, 4P):   xT (P fp32) -> Zb (2P bf16) -> yT (P fp32)  (serial reuse)
  //   region B [4P, 6P):  Fr (P bf16) -> Or
  //   region C [6P, 8P):  Fi (P bf16) -> Oi
  //   Bc at 8P: 2*589824 bf16
  const size_t need = 8 * P + 2 * 589824 * sizeof(ushort_t);  // 203,685,888 B
  if (ws_size < need) return;
  char* base = (char*)d_ws;
  float*    xT = (float*)base;
  ushort_t* Zb = (ushort_t*)base;
  float*    yT = (float*)base;
  ushort_t* Fr = (ushort_t*)(base + 4 * P);
  ushort_t* Fi = (ushort_t*)(base + 6 * P);
  ushort_t* Bc = (ushort_t*)(base + 8 * P);

  hipLaunchKernelGGL(prep_kernel, dim3(4608), dim3(256), 0, stream, w1, w2, Bc);
  // x (b,n,c) -> xT (b,c,n)
  hipLaunchKernelGGL(transpose_kernel, dim3(C_TOT / 64, N_SEQ / 64, B_BATCH),
                     dim3(256), 0, stream, x, xT, N_SEQ, C_TOT);
  hipLaunchKernelGGL(fft_fwd_kernel, dim3(C_TOT / 2, B_BATCH), dim3(512), 0,
                     stream, xT, Fr, Fi);
  hipLaunchKernelGGL(dft4t_kernel, dim3(N_SEQ / 64, NBLK, B_BATCH), dim3(256),
                     0, stream, Fr, Fi, Zb);
  hipLaunchKernelGGL(mlp_kernel, dim3(N_SEQ / 64, NBLK, B_BATCH), dim3(256),
                     0, stream, Zb, Bc, b1, b2, Fr, Fi);   // Or/Oi overwrite Fr/Fi
  hipLaunchKernelGGL(dft4_inv_kernel, dim3((B_BATCH * BS * N_SEQ / 8) / 256),
                     dim3(256), 0, stream, Fr, Fi);
  hipLaunchKernelGGL(fft_inv_kernel, dim3(C_TOT / 2, B_BATCH), dim3(512), 0,
                     stream, Fr, Fi, yT);
  // yT (b,c,n) -> out (b,n,c)
  hipLaunchKernelGGL(transpose_kernel, dim3(N_SEQ / 64, C_TOT / 64, B_BATCH),
                     dim3(256), 0, stream, yT, out, C_TOT, N_SEQ);
}